// Round 3
// baseline (173.007 us; speedup 1.0000x reference)
//
#include <hip/hip_runtime.h>
#include <hip/hip_bf16.h>

// Problem constants (B=4, S=1024, d=512, H=8, hd=64)
#define BB 4
#define SS 1024
#define DD 512
#define HH 8
#define HD 64

typedef __attribute__((ext_vector_type(8))) short bf16x8;
typedef __attribute__((ext_vector_type(4))) float f32x4;

// fp32 -> bf16 round-to-nearest-even (finite inputs)
static __device__ __forceinline__ unsigned short f2b(float f) {
  union { float f; unsigned int u; } c; c.f = f;
  return (unsigned short)((c.u + 0x7fffu + ((c.u >> 16) & 1u)) >> 16);
}

// ---------------------------------------------------------------------------
// Fused prep (one dispatch, 3968 blocks):
//  [0,1024):    x fp32 -> bf16 (2M)
//  [1024,1280): in_proj_w q|k rows -> bf16 (512K)
//  [1280,1408): out_w -> bf16 (256K)
//  [1408,3456): mask bit-pack: 8 fp32 -> 1 byte
//  [3456,3968): V [B,S,H,hd] fp32 -> Vt [B,H,hd,S] bf16
// ---------------------------------------------------------------------------
__global__ __launch_bounds__(256) void prep(
    const float* __restrict__ x, const float* __restrict__ W1,
    const float* __restrict__ Wo, const float* __restrict__ Mmask,
    const float* __restrict__ V, unsigned short* __restrict__ xb,
    unsigned short* __restrict__ W1b, unsigned short* __restrict__ Wob,
    unsigned char* __restrict__ Mpack, unsigned short* __restrict__ Vt) {
  __shared__ float Ls[64][65];
  const int bid = blockIdx.x;
  const int tid = threadIdx.x;

  if (bid < 1408) {
    const float* src; unsigned short* dst; size_t off;
    if (bid < 1024) { src = x;  dst = xb;  off = ((size_t)bid * 256 + tid) * 8; }
    else if (bid < 1280) { src = W1; dst = W1b; off = ((size_t)(bid - 1024) * 256 + tid) * 8; }
    else { src = Wo; dst = Wob; off = ((size_t)(bid - 1280) * 256 + tid) * 8; }
    const float4 a = *(const float4*)(src + off);
    const float4 b = *(const float4*)(src + off + 4);
    union { unsigned short s[8]; uint4 v; } o;
    o.s[0] = f2b(a.x); o.s[1] = f2b(a.y); o.s[2] = f2b(a.z); o.s[3] = f2b(a.w);
    o.s[4] = f2b(b.x); o.s[5] = f2b(b.y); o.s[6] = f2b(b.z); o.s[7] = f2b(b.w);
    *(uint4*)(dst + off) = o.v;
  } else if (bid < 3456) {
    const size_t g = (size_t)(bid - 1408) * 256 + tid;
    const float4 a = *(const float4*)(Mmask + g * 8);
    const float4 b = *(const float4*)(Mmask + g * 8 + 4);
    unsigned v = 0;
    v |= (a.x > 0.5f) ? 1u : 0u;   v |= (a.y > 0.5f) ? 2u : 0u;
    v |= (a.z > 0.5f) ? 4u : 0u;   v |= (a.w > 0.5f) ? 8u : 0u;
    v |= (b.x > 0.5f) ? 16u : 0u;  v |= (b.y > 0.5f) ? 32u : 0u;
    v |= (b.z > 0.5f) ? 64u : 0u;  v |= (b.w > 0.5f) ? 128u : 0u;
    Mpack[g] = (unsigned char)v;
  } else {
    const int id = bid - 3456;
    const int s0 = (id & 15) * 64, h = (id >> 4) & 7, b = id >> 7;
    {
      const int r = tid >> 2, cs = (tid & 3) * 16;
      const float* src = V + ((size_t)((b * SS + s0 + r) * HH) + h) * HD + cs;
#pragma unroll
      for (int j = 0; j < 4; j++) {
        const float4 v = *(const float4*)(src + j * 4);
        Ls[r][cs + j * 4 + 0] = v.x; Ls[r][cs + j * 4 + 1] = v.y;
        Ls[r][cs + j * 4 + 2] = v.z; Ls[r][cs + j * 4 + 3] = v.w;
      }
    }
    __syncthreads();
    {
      const int d = tid >> 2, ss = (tid & 3) * 16;
      union { unsigned short s[16]; uint4 v[2]; } o;
#pragma unroll
      for (int j = 0; j < 16; j++) o.s[j] = f2b(Ls[ss + j][d]);
      unsigned short* dst =
          Vt + ((size_t)((b * HH + h) * HD + d)) * SS + s0 + ss;
      *(uint4*)dst = o.v[0];
      *(uint4*)(dst + 8) = o.v[1];
    }
  }
}

// ---------------------------------------------------------------------------
// GEMM1: qkb[4096,1024](bf16) = xb(bf16) @ W1b(bf16)^T + bias  (unchanged)
// ---------------------------------------------------------------------------
__global__ __launch_bounds__(256) void gemm_qk(
    const unsigned short* __restrict__ xb, const unsigned short* __restrict__ W1b,
    const float* __restrict__ bias, unsigned short* __restrict__ qkb) {
  __shared__ unsigned short As[128][40];
  __shared__ unsigned short Bs[64][40];
  const int tid = threadIdx.x;
  const int lane = tid & 63, wave = tid >> 6;
  const int l16 = lane & 15, quad = lane >> 4;
  const int row0 = blockIdx.y * 128, col0 = blockIdx.x * 64;

  f32x4 acc[2][4];
#pragma unroll
  for (int i = 0; i < 2; i++)
#pragma unroll
    for (int j = 0; j < 4; j++) acc[i][j] = (f32x4){0.f, 0.f, 0.f, 0.f};

  const int ra = tid >> 1, csa = (tid & 1) * 16;
  const int rb = tid >> 2, csb = (tid & 3) * 8;
  const unsigned short* ap = xb + (size_t)(row0 + ra) * DD + csa;
  const unsigned short* bp = W1b + (size_t)(col0 + rb) * DD + csb;

  uint4 pa0 = *(const uint4*)ap, pa1 = *(const uint4*)(ap + 8);
  uint4 pb = *(const uint4*)bp;

  for (int k0 = 0; k0 < DD; k0 += 32) {
    __syncthreads();
    *(uint4*)&As[ra][csa] = pa0;
    *(uint4*)&As[ra][csa + 8] = pa1;
    *(uint4*)&Bs[rb][csb] = pb;
    __syncthreads();
    if (k0 + 32 < DD) {  // prefetch next slab; vmcnt waits land next iter
      pa0 = *(const uint4*)(ap + k0 + 32);
      pa1 = *(const uint4*)(ap + k0 + 40);
      pb = *(const uint4*)(bp + k0 + 32);
    }

    const bf16x8 a0 = *(const bf16x8*)&As[wave * 32 + l16][quad * 8];
    const bf16x8 a1 = *(const bf16x8*)&As[wave * 32 + 16 + l16][quad * 8];
#pragma unroll
    for (int nt = 0; nt < 4; nt++) {
      const bf16x8 bb = *(const bf16x8*)&Bs[nt * 16 + l16][quad * 8];
      acc[0][nt] = __builtin_amdgcn_mfma_f32_16x16x32_bf16(a0, bb, acc[0][nt], 0, 0, 0);
      acc[1][nt] = __builtin_amdgcn_mfma_f32_16x16x32_bf16(a1, bb, acc[1][nt], 0, 0, 0);
    }
  }

#pragma unroll
  for (int nt = 0; nt < 4; nt++) {
    const int col = col0 + nt * 16 + l16;
    const float bv = bias[col];
    const float scale = (col < DD) ? 0.125f : 1.0f;
#pragma unroll
    for (int mi = 0; mi < 2; mi++)
#pragma unroll
      for (int reg = 0; reg < 4; reg++) {
        const int row = row0 + wave * 32 + mi * 16 + quad * 4 + reg;
        qkb[(size_t)row * 1024 + col] = f2b((acc[mi][nt][reg] + bv) * scale);
      }
  }
}

// ---------------------------------------------------------------------------
// GEMM3: out[4096,512](fp32) = attnb(bf16) @ Wob(bf16)^T + out_b  (unchanged)
// ---------------------------------------------------------------------------
__global__ __launch_bounds__(256) void gemm_out(
    const unsigned short* __restrict__ Ab, const unsigned short* __restrict__ Wob,
    const float* __restrict__ bias, float* __restrict__ out) {
  __shared__ unsigned short As[64][40];
  __shared__ unsigned short Bs[64][40];
  const int tid = threadIdx.x;
  const int lane = tid & 63, wave = tid >> 6;
  const int l16 = lane & 15, quad = lane >> 4;
  const int row0 = blockIdx.y * 64, col0 = blockIdx.x * 64;

  f32x4 acc[4];
#pragma unroll
  for (int j = 0; j < 4; j++) acc[j] = (f32x4){0.f, 0.f, 0.f, 0.f};

  const int r = tid >> 2, cs = (tid & 3) * 8;
  const unsigned short* ap = Ab + (size_t)(row0 + r) * DD + cs;
  const unsigned short* bp = Wob + (size_t)(col0 + r) * DD + cs;

  uint4 pa = *(const uint4*)ap;
  uint4 pb = *(const uint4*)bp;

  for (int k0 = 0; k0 < DD; k0 += 32) {
    __syncthreads();
    *(uint4*)&As[r][cs] = pa;
    *(uint4*)&Bs[r][cs] = pb;
    __syncthreads();
    if (k0 + 32 < DD) {
      pa = *(const uint4*)(ap + k0 + 32);
      pb = *(const uint4*)(bp + k0 + 32);
    }

    const bf16x8 a0 = *(const bf16x8*)&As[wave * 16 + l16][quad * 8];
#pragma unroll
    for (int nt = 0; nt < 4; nt++) {
      const bf16x8 bb = *(const bf16x8*)&Bs[nt * 16 + l16][quad * 8];
      acc[nt] = __builtin_amdgcn_mfma_f32_16x16x32_bf16(a0, bb, acc[nt], 0, 0, 0);
    }
  }

#pragma unroll
  for (int nt = 0; nt < 4; nt++) {
    const int col = col0 + nt * 16 + l16;
    const float bv = bias[col];
#pragma unroll
    for (int reg = 0; reg < 4; reg++) {
      const int row = row0 + wave * 16 + quad * 4 + reg;
      out[(size_t)row * DD + col] = acc[nt][reg] + bv;
    }
  }
}

// ---------------------------------------------------------------------------
// Fused split-k flash attention (r9): direct-from-L2 operand loads, no LDS
// staging, NO barriers in the main loop.
//  - Q, K, V fragments are per-lane 16B bf16x8 global loads in exact MFMA
//    operand layout. K slab (4MB of qkb) and Vt (4MB) are L2-resident;
//    each 64x64 tile row for one head is exactly one 128B line, and the
//    4-way wave redundancy within a block hits L1 (32KB/CU).
//  - Only LDS use in the loop: wave-private P^T -> P repack (in-wave DS
//    ordering; no cross-wave sharing, hence no barriers).
//  - Waves 0-3 (sp=0) own k-range [0,512), waves 4-7 (sp=1) [512,1024);
//    epilogue combines the two halves through LDS (PB reused as fp32
//    O-exchange) and writes attnb bf16 directly.
//  - q pre-scaled 0.125 in gemm_qk -> exp(a) directly; no max shift,
//    no eps*Z term (rel ~2e-8) — same numerics as r8.
// ---------------------------------------------------------------------------
__global__ __launch_bounds__(512, 4) void flash_attn_fused(
    const unsigned short* __restrict__ qkb, const unsigned short* __restrict__ Vt,
    const unsigned char* __restrict__ Mpack, unsigned short* __restrict__ attnb) {
  __shared__ unsigned short PB[2][64][72];  // [sp] P buffers; epilogue: fp32 O
  __shared__ float SmS[2][64];              // per-half row denominators

  const int tid = threadIdx.x;
  const int lane = tid & 63, wave = tid >> 6;
  const int l16 = lane & 15, quad = lane >> 4;
  const int wq = wave & 3, sp = wave >> 2;
  const int q0 = blockIdx.x * 64;
  const int h = blockIdx.y;
  const int b = blockIdx.z;

  // Q fragments: lane (l16,quad) holds Q[q0+wq*16+l16][h*64 + quad*8 (+32)]
  const unsigned short* qp =
      qkb + (size_t)(b * SS + q0 + wq * 16 + l16) * 1024 + h * HD + quad * 8;
  const bf16x8 bQ0 = *(const bf16x8*)qp;
  const bf16x8 bQ1 = *(const bf16x8*)(qp + 32);

  // mask bits: q = q0+wq*16+l16, this half's 8 k-tiles (8 B/iter)
  const unsigned char* mp =
      Mpack + (size_t)(b * SS + q0 + wq * 16 + l16) * 128 + sp * 64;

  // K base: row = key index (l16 within tile), cols DD+h*64+quad*8 (+32)
  const unsigned short* kb =
      qkb + (size_t)(b * SS + sp * 512 + l16) * 1024 + DD + h * HD + quad * 8;
  // V base: row = d (l16 within dt-block), cols = key offset quad*8 (+32)
  const unsigned short* vb =
      Vt + ((size_t)((b * HH + h) * HD + l16)) * SS + sp * 512 + quad * 8;

  unsigned short(*Ps)[72] = (unsigned short(*)[72]) & PB[sp][wq * 16][0];

  float Smp = 0.f;
  f32x4 O[4];
#pragma unroll
  for (int i = 0; i < 4; i++) O[i] = (f32x4){0.f, 0.f, 0.f, 0.f};

#pragma unroll 2
  for (int i = 0; i < 8; i++) {
    const uint2 pm = *(const uint2*)(mp + i * 8);

    // ---- S^T tiles: D[s=quad*4+reg][q=l16]; exp, mask-bit select, P pack ----
#pragma unroll
    for (int t = 0; t < 4; t++) {
      const unsigned short* kt = kb + (size_t)(i * 64 + t * 16) * 1024;
      const bf16x8 aK0 = *(const bf16x8*)kt;
      const bf16x8 aK1 = *(const bf16x8*)(kt + 32);
      f32x4 a = (f32x4){0.f, 0.f, 0.f, 0.f};
      a = __builtin_amdgcn_mfma_f32_16x16x32_bf16(aK0, bQ0, a, 0, 0, 0);
      a = __builtin_amdgcn_mfma_f32_16x16x32_bf16(aK1, bQ1, a, 0, 0, 0);
      const unsigned nib =
          ((t < 2 ? pm.x : pm.y) >> ((t & 1) * 16 + quad * 4)) & 0xFu;
      float e0 = __expf(a[0]); e0 = (nib & 1u) ? e0 : 0.f;
      float e1 = __expf(a[1]); e1 = (nib & 2u) ? e1 : 0.f;
      float e2 = __expf(a[2]); e2 = (nib & 4u) ? e2 : 0.f;
      float e3 = __expf(a[3]); e3 = (nib & 8u) ? e3 : 0.f;
      Smp += (e0 + e1) + (e2 + e3);
      uint2 w;
      w.x = (unsigned)f2b(e0) | ((unsigned)f2b(e1) << 16);
      w.y = (unsigned)f2b(e2) | ((unsigned)f2b(e3) << 16);
      *(uint2*)&Ps[l16][t * 16 + quad * 4] = w;  // ds_write_b64, wave-private
    }

    // ---- O += P @ V (P via wave-private LDS repack; V direct from L2) ----
    const bf16x8 aP0 = *(const bf16x8*)&Ps[l16][quad * 8];
    const bf16x8 aP1 = *(const bf16x8*)&Ps[l16][32 + quad * 8];
#pragma unroll
    for (int dt = 0; dt < 4; dt++) {
      const unsigned short* vt = vb + (size_t)(dt * 16) * 1024 + i * 64;
      const bf16x8 bV0 = *(const bf16x8*)vt;
      const bf16x8 bV1 = *(const bf16x8*)(vt + 32);
      O[dt] = __builtin_amdgcn_mfma_f32_16x16x32_bf16(aP0, bV0, O[dt], 0, 0, 0);
      O[dt] = __builtin_amdgcn_mfma_f32_16x16x32_bf16(aP1, bV1, O[dt], 0, 0, 0);
    }
  }

  // ---- epilogue: in-block split-k combine through LDS ----
  Smp += __shfl_xor(Smp, 16);
  Smp += __shfl_xor(Smp, 32);
  if (lane < 16) SmS[sp][wq * 16 + lane] = Smp;

  __syncthreads();  // all P reads drained; SmS visible
  float* Of = reinterpret_cast<float*>(&PB[0][0][0]);  // 16 KB <= 18.4 KB
  if (sp == 1) {
#pragma unroll
    for (int dt = 0; dt < 4; dt++)
#pragma unroll
      for (int reg = 0; reg < 4; reg++)
        Of[(wq * 16 + quad * 4 + reg) * 64 + dt * 16 + l16] = O[dt][reg];
  }
  __syncthreads();

  if (sp == 0) {
    float inv[4];
#pragma unroll
    for (int reg = 0; reg < 4; reg++) {
      const int ql = wq * 16 + quad * 4 + reg;
      inv[reg] = 1.0f / (SmS[0][ql] + SmS[1][ql] + 1e-12f);
    }
#pragma unroll
    for (int dt = 0; dt < 4; dt++)
#pragma unroll
      for (int reg = 0; reg < 4; reg++) {
        const int ql = wq * 16 + quad * 4 + reg;
        const float v = (O[dt][reg] + Of[ql * 64 + dt * 16 + l16]) * inv[reg];
        attnb[(size_t)(b * SS + q0 + ql) * DD + h * HD + dt * 16 + l16] = f2b(v);
      }
  }
}

// ---------------------------------------------------------------------------
extern "C" void kernel_launch(void* const* d_in, const int* in_sizes, int n_in,
                              void* d_out, int out_size, void* d_ws,
                              size_t ws_size, hipStream_t stream) {
  const float* x = (const float*)d_in[0];          // [4,1024,512]
  const float* V = (const float*)d_in[1];          // [4,1024,8,64]
  const float* Mmask = (const float*)d_in[2];      // [4,1024,1024]
  const float* in_proj_w = (const float*)d_in[3];  // [1536,512]
  const float* in_proj_b = (const float*)d_in[4];  // [1536]
  const float* out_w = (const float*)d_in[5];      // [512,512]
  const float* out_b = (const float*)d_in[6];      // [512]
  float* out = (float*)d_out;                      // [4,1024,512]

  unsigned char* ws = (unsigned char*)d_ws;
  unsigned short* qkb   = (unsigned short*)(ws);                     // 8 MB
  unsigned short* xb    = (unsigned short*)(ws + (8ull << 20));      // 4 MB
  unsigned short* W1b   = (unsigned short*)(ws + (12ull << 20));     // 1 MB
  unsigned short* Wob   = (unsigned short*)(ws + (13ull << 20));     // 0.5 MB
  unsigned short* Vt    = (unsigned short*)(ws + (14ull << 20));     // 4 MB
  unsigned short* attnb = (unsigned short*)(ws + (18ull << 20));     // 4 MB
  unsigned char*  Mpack = ws + (38ull << 20) + (256u << 10);         // 512 KB

  prep<<<3968, 256, 0, stream>>>(x, in_proj_w, out_w, Mmask, V,
                                 xb, W1b, Wob, Mpack, Vt);
  gemm_qk<<<dim3(16, 32), 256, 0, stream>>>(xb, W1b, in_proj_b, qkb);
  flash_attn_fused<<<dim3(SS / 64, HH, BB), 512, 0, stream>>>(
      qkb, Vt, Mpack, attnb);
  gemm_out<<<dim3(8, 64), 256, 0, stream>>>(attnb, Wob, out_b, out);
}

// Round 4
// 138.780 us; speedup vs baseline: 1.2466x; 1.2466x over previous
//
#include <hip/hip_runtime.h>
#include <hip/hip_bf16.h>

// Problem constants (B=4, S=1024, d=512, H=8, hd=64)
#define BB 4
#define SS 1024
#define DD 512
#define HH 8
#define HD 64

typedef __attribute__((ext_vector_type(8))) short bf16x8;
typedef __attribute__((ext_vector_type(4))) float f32x4;

// fp32 -> bf16 round-to-nearest-even (finite inputs)
static __device__ __forceinline__ unsigned short f2b(float f) {
  union { float f; unsigned int u; } c; c.f = f;
  return (unsigned short)((c.u + 0x7fffu + ((c.u >> 16) & 1u)) >> 16);
}

// ---------------------------------------------------------------------------
// Fused prep (one dispatch, 3968 blocks):
//  [0,1024):    x fp32 -> bf16 (2M)
//  [1024,1280): in_proj_w q|k rows -> bf16 (512K)
//  [1280,1408): out_w -> bf16 (256K)
//  [1408,3456): mask bit-pack: 8 fp32 -> 1 byte
//  [3456,3968): V [B,S,H,hd] fp32 -> Vt [B,H,hd,S] bf16
// ---------------------------------------------------------------------------
__global__ __launch_bounds__(256) void prep(
    const float* __restrict__ x, const float* __restrict__ W1,
    const float* __restrict__ Wo, const float* __restrict__ Mmask,
    const float* __restrict__ V, unsigned short* __restrict__ xb,
    unsigned short* __restrict__ W1b, unsigned short* __restrict__ Wob,
    unsigned char* __restrict__ Mpack, unsigned short* __restrict__ Vt) {
  __shared__ float Ls[64][65];
  const int bid = blockIdx.x;
  const int tid = threadIdx.x;

  if (bid < 1408) {
    const float* src; unsigned short* dst; size_t off;
    if (bid < 1024) { src = x;  dst = xb;  off = ((size_t)bid * 256 + tid) * 8; }
    else if (bid < 1280) { src = W1; dst = W1b; off = ((size_t)(bid - 1024) * 256 + tid) * 8; }
    else { src = Wo; dst = Wob; off = ((size_t)(bid - 1280) * 256 + tid) * 8; }
    const float4 a = *(const float4*)(src + off);
    const float4 b = *(const float4*)(src + off + 4);
    union { unsigned short s[8]; uint4 v; } o;
    o.s[0] = f2b(a.x); o.s[1] = f2b(a.y); o.s[2] = f2b(a.z); o.s[3] = f2b(a.w);
    o.s[4] = f2b(b.x); o.s[5] = f2b(b.y); o.s[6] = f2b(b.z); o.s[7] = f2b(b.w);
    *(uint4*)(dst + off) = o.v;
  } else if (bid < 3456) {
    const size_t g = (size_t)(bid - 1408) * 256 + tid;
    const float4 a = *(const float4*)(Mmask + g * 8);
    const float4 b = *(const float4*)(Mmask + g * 8 + 4);
    unsigned v = 0;
    v |= (a.x > 0.5f) ? 1u : 0u;   v |= (a.y > 0.5f) ? 2u : 0u;
    v |= (a.z > 0.5f) ? 4u : 0u;   v |= (a.w > 0.5f) ? 8u : 0u;
    v |= (b.x > 0.5f) ? 16u : 0u;  v |= (b.y > 0.5f) ? 32u : 0u;
    v |= (b.z > 0.5f) ? 64u : 0u;  v |= (b.w > 0.5f) ? 128u : 0u;
    Mpack[g] = (unsigned char)v;
  } else {
    const int id = bid - 3456;
    const int s0 = (id & 15) * 64, h = (id >> 4) & 7, b = id >> 7;
    {
      const int r = tid >> 2, cs = (tid & 3) * 16;
      const float* src = V + ((size_t)((b * SS + s0 + r) * HH) + h) * HD + cs;
#pragma unroll
      for (int j = 0; j < 4; j++) {
        const float4 v = *(const float4*)(src + j * 4);
        Ls[r][cs + j * 4 + 0] = v.x; Ls[r][cs + j * 4 + 1] = v.y;
        Ls[r][cs + j * 4 + 2] = v.z; Ls[r][cs + j * 4 + 3] = v.w;
      }
    }
    __syncthreads();
    {
      const int d = tid >> 2, ss = (tid & 3) * 16;
      union { unsigned short s[16]; uint4 v[2]; } o;
#pragma unroll
      for (int j = 0; j < 16; j++) o.s[j] = f2b(Ls[ss + j][d]);
      unsigned short* dst =
          Vt + ((size_t)((b * HH + h) * HD + d)) * SS + s0 + ss;
      *(uint4*)dst = o.v[0];
      *(uint4*)(dst + 8) = o.v[1];
    }
  }
}

// ---------------------------------------------------------------------------
// GEMM1: qkb[4096,1024](bf16) = xb(bf16) @ W1b(bf16)^T + bias  (unchanged)
// ---------------------------------------------------------------------------
__global__ __launch_bounds__(256) void gemm_qk(
    const unsigned short* __restrict__ xb, const unsigned short* __restrict__ W1b,
    const float* __restrict__ bias, unsigned short* __restrict__ qkb) {
  __shared__ unsigned short As[128][40];
  __shared__ unsigned short Bs[64][40];
  const int tid = threadIdx.x;
  const int lane = tid & 63, wave = tid >> 6;
  const int l16 = lane & 15, quad = lane >> 4;
  const int row0 = blockIdx.y * 128, col0 = blockIdx.x * 64;

  f32x4 acc[2][4];
#pragma unroll
  for (int i = 0; i < 2; i++)
#pragma unroll
    for (int j = 0; j < 4; j++) acc[i][j] = (f32x4){0.f, 0.f, 0.f, 0.f};

  const int ra = tid >> 1, csa = (tid & 1) * 16;
  const int rb = tid >> 2, csb = (tid & 3) * 8;
  const unsigned short* ap = xb + (size_t)(row0 + ra) * DD + csa;
  const unsigned short* bp = W1b + (size_t)(col0 + rb) * DD + csb;

  uint4 pa0 = *(const uint4*)ap, pa1 = *(const uint4*)(ap + 8);
  uint4 pb = *(const uint4*)bp;

  for (int k0 = 0; k0 < DD; k0 += 32) {
    __syncthreads();
    *(uint4*)&As[ra][csa] = pa0;
    *(uint4*)&As[ra][csa + 8] = pa1;
    *(uint4*)&Bs[rb][csb] = pb;
    __syncthreads();
    if (k0 + 32 < DD) {  // prefetch next slab; vmcnt waits land next iter
      pa0 = *(const uint4*)(ap + k0 + 32);
      pa1 = *(const uint4*)(ap + k0 + 40);
      pb = *(const uint4*)(bp + k0 + 32);
    }

    const bf16x8 a0 = *(const bf16x8*)&As[wave * 32 + l16][quad * 8];
    const bf16x8 a1 = *(const bf16x8*)&As[wave * 32 + 16 + l16][quad * 8];
#pragma unroll
    for (int nt = 0; nt < 4; nt++) {
      const bf16x8 bb = *(const bf16x8*)&Bs[nt * 16 + l16][quad * 8];
      acc[0][nt] = __builtin_amdgcn_mfma_f32_16x16x32_bf16(a0, bb, acc[0][nt], 0, 0, 0);
      acc[1][nt] = __builtin_amdgcn_mfma_f32_16x16x32_bf16(a1, bb, acc[1][nt], 0, 0, 0);
    }
  }

#pragma unroll
  for (int nt = 0; nt < 4; nt++) {
    const int col = col0 + nt * 16 + l16;
    const float bv = bias[col];
    const float scale = (col < DD) ? 0.125f : 1.0f;
#pragma unroll
    for (int mi = 0; mi < 2; mi++)
#pragma unroll
      for (int reg = 0; reg < 4; reg++) {
        const int row = row0 + wave * 32 + mi * 16 + quad * 4 + reg;
        qkb[(size_t)row * 1024 + col] = f2b((acc[mi][nt][reg] + bv) * scale);
      }
  }
}

// ---------------------------------------------------------------------------
// GEMM3: out[4096,512](fp32) = attnb(bf16) @ Wob(bf16)^T + out_b  (unchanged)
// ---------------------------------------------------------------------------
__global__ __launch_bounds__(256) void gemm_out(
    const unsigned short* __restrict__ Ab, const unsigned short* __restrict__ Wob,
    const float* __restrict__ bias, float* __restrict__ out) {
  __shared__ unsigned short As[64][40];
  __shared__ unsigned short Bs[64][40];
  const int tid = threadIdx.x;
  const int lane = tid & 63, wave = tid >> 6;
  const int l16 = lane & 15, quad = lane >> 4;
  const int row0 = blockIdx.y * 64, col0 = blockIdx.x * 64;

  f32x4 acc[4];
#pragma unroll
  for (int j = 0; j < 4; j++) acc[j] = (f32x4){0.f, 0.f, 0.f, 0.f};

  const int r = tid >> 2, cs = (tid & 3) * 8;
  const unsigned short* ap = Ab + (size_t)(row0 + r) * DD + cs;
  const unsigned short* bp = Wob + (size_t)(col0 + r) * DD + cs;

  uint4 pa = *(const uint4*)ap;
  uint4 pb = *(const uint4*)bp;

  for (int k0 = 0; k0 < DD; k0 += 32) {
    __syncthreads();
    *(uint4*)&As[r][cs] = pa;
    *(uint4*)&Bs[r][cs] = pb;
    __syncthreads();
    if (k0 + 32 < DD) {
      pa = *(const uint4*)(ap + k0 + 32);
      pb = *(const uint4*)(bp + k0 + 32);
    }

    const bf16x8 a0 = *(const bf16x8*)&As[wave * 16 + l16][quad * 8];
#pragma unroll
    for (int nt = 0; nt < 4; nt++) {
      const bf16x8 bb = *(const bf16x8*)&Bs[nt * 16 + l16][quad * 8];
      acc[nt] = __builtin_amdgcn_mfma_f32_16x16x32_bf16(a0, bb, acc[nt], 0, 0, 0);
    }
  }

#pragma unroll
  for (int nt = 0; nt < 4; nt++) {
    const int col = col0 + nt * 16 + l16;
    const float bv = bias[col];
#pragma unroll
    for (int reg = 0; reg < 4; reg++) {
      const int row = row0 + wave * 16 + quad * 4 + reg;
      out[(size_t)row * DD + col] = acc[nt][reg] + bv;
    }
  }
}

// ---------------------------------------------------------------------------
// Fused split-k flash attention (r10): staged K/V (r8 structure, proven) but
// each wave owns 32 q-rows as TWO 16-row groups -> every K/V ds_read_b128
// feeds 2 MFMAs instead of 1, halving the dominant LDS-read term.
//  - 256 threads / 4 waves: waves 0,1 = k-half 0 (keys [0,512)), waves 2,3
//    = k-half 1. Wave wg owns q-rows [wg*32, wg*32+32).
//  - Both halves' K/V tiles staged per iter (32 KB), register-prefetched.
//  - Q fragments loaded once directly from global (L2-resident, one-time).
//  - P buffer is dedicated LDS (no aliasing), wave-private rows.
//  - Epilogue: half-1 waves dump fp32 O into Pbuf, half-0 waves combine,
//    normalize by 1/(Sm0+Sm1), write attnb bf16.
//  - q pre-scaled 0.125 in gemm_qk -> exp(a) directly; no max shift,
//    no eps*Z term (rel ~2e-8) — same numerics as r8.
// LDS 55.8 KB -> 2 blocks/CU (8 waves/CU); grid 512 blocks = 2/CU exactly.
// ---------------------------------------------------------------------------
__global__ __launch_bounds__(256) void flash_attn_fused(
    const unsigned short* __restrict__ qkb, const unsigned short* __restrict__ Vt,
    const unsigned char* __restrict__ Mpack, unsigned short* __restrict__ attnb) {
  __shared__ unsigned short Ks[2][64][72];   // K tiles, both halves
  __shared__ unsigned short Vs[2][64][72];   // V tiles [d][s], both halves
  __shared__ unsigned short Pbuf[128][72];   // per-wave P rows; epilogue: fp32 O
  __shared__ float SmS[2][64];               // per-half row denominators

  const int tid = threadIdx.x;
  const int lane = tid & 63, wave = tid >> 6;
  const int l16 = lane & 15, quad = lane >> 4;
  const int wg = wave & 1, sp = wave >> 1;
  const int q0 = blockIdx.x * 64;
  const int h = blockIdx.y;
  const int b = blockIdx.z;

  // Q fragments for both 16-row groups, direct from global (one-time):
  // group a rows q0+wg*32+l16, group b rows +16; cols h*64 + quad*8 (+32)
  const unsigned short* qp =
      qkb + (size_t)(b * SS + q0 + wg * 32 + l16) * 1024 + h * HD + quad * 8;
  const bf16x8 bQa0 = *(const bf16x8*)qp;
  const bf16x8 bQa1 = *(const bf16x8*)(qp + 32);
  const bf16x8 bQb0 = *(const bf16x8*)(qp + 16 * 1024);
  const bf16x8 bQb1 = *(const bf16x8*)(qp + 16 * 1024 + 32);

  // mask base pointers for the two q-groups (this half's 8 k-tiles)
  const unsigned char* mpa =
      Mpack + (size_t)(b * SS + q0 + wg * 32 + l16) * 128 + sp * 64;
  const unsigned char* mpb = mpa + 16 * 128;
  uint2 pma = *(const uint2*)mpa;
  uint2 pmb = *(const uint2*)mpb;

  // per-thread staging source pointers (r=row-in-tile, cs=col-pair start)
  const int r = tid >> 2, cs = (tid & 3) * 16;
  const unsigned short* kp0 =
      qkb + (size_t)(b * SS + r) * 1024 + DD + h * HD + cs;   // keys [0,512)
  const unsigned short* kp1 = kp0 + (size_t)512 * 1024;       // keys [512,1024)
  const unsigned short* vp0 =
      Vt + ((size_t)((b * HH + h) * HD + r)) * SS + cs;
  const unsigned short* vp1 = vp0 + 512;

  // prefetch tile 0 (both halves): 8 x uint4
  uint4 pk0a = *(const uint4*)kp0, pk0b = *(const uint4*)(kp0 + 8);
  uint4 pk1a = *(const uint4*)kp1, pk1b = *(const uint4*)(kp1 + 8);
  uint4 pv0a = *(const uint4*)vp0, pv0b = *(const uint4*)(vp0 + 8);
  uint4 pv1a = *(const uint4*)vp1, pv1b = *(const uint4*)(vp1 + 8);

  unsigned short(*Ps)[72] = (unsigned short(*)[72]) & Pbuf[wave * 32][0];

  float Sma = 0.f, Smb = 0.f;
  f32x4 Oa[4], Ob[4];
#pragma unroll
  for (int i = 0; i < 4; i++) {
    Oa[i] = (f32x4){0.f, 0.f, 0.f, 0.f};
    Ob[i] = (f32x4){0.f, 0.f, 0.f, 0.f};
  }

  for (int i = 0; i < 8; i++) {
    __syncthreads();  // prior iter's Ks/Vs frag reads complete
    *(uint4*)&Ks[0][r][cs] = pk0a;
    *(uint4*)&Ks[0][r][cs + 8] = pk0b;
    *(uint4*)&Ks[1][r][cs] = pk1a;
    *(uint4*)&Ks[1][r][cs + 8] = pk1b;
    *(uint4*)&Vs[0][r][cs] = pv0a;
    *(uint4*)&Vs[0][r][cs + 8] = pv0b;
    *(uint4*)&Vs[1][r][cs] = pv1a;
    *(uint4*)&Vs[1][r][cs + 8] = pv1b;
    __syncthreads();

    const uint2 ma = pma, mb = pmb;
    if (i < 7) {  // prefetch tile i+1; latency hidden by compute below
      const size_t ko = (size_t)(i + 1) * 64 * 1024;
      pk0a = *(const uint4*)(kp0 + ko);
      pk0b = *(const uint4*)(kp0 + ko + 8);
      pk1a = *(const uint4*)(kp1 + ko);
      pk1b = *(const uint4*)(kp1 + ko + 8);
      pv0a = *(const uint4*)(vp0 + (i + 1) * 64);
      pv0b = *(const uint4*)(vp0 + (i + 1) * 64 + 8);
      pv1a = *(const uint4*)(vp1 + (i + 1) * 64);
      pv1b = *(const uint4*)(vp1 + (i + 1) * 64 + 8);
      pma = *(const uint2*)(mpa + (i + 1) * 8);
      pmb = *(const uint2*)(mpb + (i + 1) * 8);
    }

    // ---- S^T tiles: D[s=quad*4+reg][q=l16]; K frag shared by both q-groups
#pragma unroll
    for (int t = 0; t < 4; t++) {
      const bf16x8 aK0 = *(const bf16x8*)&Ks[sp][t * 16 + l16][quad * 8];
      const bf16x8 aK1 = *(const bf16x8*)&Ks[sp][t * 16 + l16][32 + quad * 8];
      f32x4 a = (f32x4){0.f, 0.f, 0.f, 0.f};
      a = __builtin_amdgcn_mfma_f32_16x16x32_bf16(aK0, bQa0, a, 0, 0, 0);
      a = __builtin_amdgcn_mfma_f32_16x16x32_bf16(aK1, bQa1, a, 0, 0, 0);
      f32x4 c = (f32x4){0.f, 0.f, 0.f, 0.f};
      c = __builtin_amdgcn_mfma_f32_16x16x32_bf16(aK0, bQb0, c, 0, 0, 0);
      c = __builtin_amdgcn_mfma_f32_16x16x32_bf16(aK1, bQb1, c, 0, 0, 0);

      const unsigned sh = (t & 1) * 16 + quad * 4;
      const unsigned niba = ((t < 2 ? ma.x : ma.y) >> sh) & 0xFu;
      const unsigned nibb = ((t < 2 ? mb.x : mb.y) >> sh) & 0xFu;
      float e0 = __expf(a[0]); e0 = (niba & 1u) ? e0 : 0.f;
      float e1 = __expf(a[1]); e1 = (niba & 2u) ? e1 : 0.f;
      float e2 = __expf(a[2]); e2 = (niba & 4u) ? e2 : 0.f;
      float e3 = __expf(a[3]); e3 = (niba & 8u) ? e3 : 0.f;
      Sma += (e0 + e1) + (e2 + e3);
      uint2 wa;
      wa.x = (unsigned)f2b(e0) | ((unsigned)f2b(e1) << 16);
      wa.y = (unsigned)f2b(e2) | ((unsigned)f2b(e3) << 16);
      *(uint2*)&Ps[l16][t * 16 + quad * 4] = wa;  // ds_write_b64, wave-private

      float g0 = __expf(c[0]); g0 = (nibb & 1u) ? g0 : 0.f;
      float g1 = __expf(c[1]); g1 = (nibb & 2u) ? g1 : 0.f;
      float g2 = __expf(c[2]); g2 = (nibb & 4u) ? g2 : 0.f;
      float g3 = __expf(c[3]); g3 = (nibb & 8u) ? g3 : 0.f;
      Smb += (g0 + g1) + (g2 + g3);
      uint2 wb;
      wb.x = (unsigned)f2b(g0) | ((unsigned)f2b(g1) << 16);
      wb.y = (unsigned)f2b(g2) | ((unsigned)f2b(g3) << 16);
      *(uint2*)&Ps[16 + l16][t * 16 + quad * 4] = wb;
    }

    // ---- O += P @ V: V frag shared by both q-groups ----
    const bf16x8 aPa0 = *(const bf16x8*)&Ps[l16][quad * 8];
    const bf16x8 aPa1 = *(const bf16x8*)&Ps[l16][32 + quad * 8];
    const bf16x8 aPb0 = *(const bf16x8*)&Ps[16 + l16][quad * 8];
    const bf16x8 aPb1 = *(const bf16x8*)&Ps[16 + l16][32 + quad * 8];
#pragma unroll
    for (int dt = 0; dt < 4; dt++) {
      const bf16x8 bV0 = *(const bf16x8*)&Vs[sp][dt * 16 + l16][quad * 8];
      const bf16x8 bV1 = *(const bf16x8*)&Vs[sp][dt * 16 + l16][32 + quad * 8];
      Oa[dt] = __builtin_amdgcn_mfma_f32_16x16x32_bf16(aPa0, bV0, Oa[dt], 0, 0, 0);
      Oa[dt] = __builtin_amdgcn_mfma_f32_16x16x32_bf16(aPa1, bV1, Oa[dt], 0, 0, 0);
      Ob[dt] = __builtin_amdgcn_mfma_f32_16x16x32_bf16(aPb0, bV0, Ob[dt], 0, 0, 0);
      Ob[dt] = __builtin_amdgcn_mfma_f32_16x16x32_bf16(aPb1, bV1, Ob[dt], 0, 0, 0);
    }
  }

  // ---- epilogue: in-block split-k combine through LDS ----
  Sma += __shfl_xor(Sma, 16);
  Sma += __shfl_xor(Sma, 32);
  Smb += __shfl_xor(Smb, 16);
  Smb += __shfl_xor(Smb, 32);
  if (lane < 16) {
    SmS[sp][wg * 32 + lane] = Sma;
    SmS[sp][wg * 32 + 16 + lane] = Smb;
  }

  __syncthreads();  // all P reads drained; SmS visible
  float* Of = reinterpret_cast<float*>(&Pbuf[0][0]);  // 16 KB <= 18.4 KB
  if (sp == 1) {
#pragma unroll
    for (int dt = 0; dt < 4; dt++)
#pragma unroll
      for (int reg = 0; reg < 4; reg++) {
        const int qa = wg * 32 + quad * 4 + reg;
        Of[qa * 64 + dt * 16 + l16] = Oa[dt][reg];
        Of[(qa + 16) * 64 + dt * 16 + l16] = Ob[dt][reg];
      }
  }
  __syncthreads();

  if (sp == 0) {
#pragma unroll
    for (int dt = 0; dt < 4; dt++)
#pragma unroll
      for (int reg = 0; reg < 4; reg++) {
        const int qa = wg * 32 + quad * 4 + reg;
        const float inva = 1.0f / (SmS[0][qa] + SmS[1][qa] + 1e-12f);
        const float invb = 1.0f / (SmS[0][qa + 16] + SmS[1][qa + 16] + 1e-12f);
        const float va = (Oa[dt][reg] + Of[qa * 64 + dt * 16 + l16]) * inva;
        const float vb = (Ob[dt][reg] + Of[(qa + 16) * 64 + dt * 16 + l16]) * invb;
        attnb[(size_t)(b * SS + q0 + qa) * DD + h * HD + dt * 16 + l16] = f2b(va);
        attnb[(size_t)(b * SS + q0 + qa + 16) * DD + h * HD + dt * 16 + l16] = f2b(vb);
      }
  }
}

// ---------------------------------------------------------------------------
extern "C" void kernel_launch(void* const* d_in, const int* in_sizes, int n_in,
                              void* d_out, int out_size, void* d_ws,
                              size_t ws_size, hipStream_t stream) {
  const float* x = (const float*)d_in[0];          // [4,1024,512]
  const float* V = (const float*)d_in[1];          // [4,1024,8,64]
  const float* Mmask = (const float*)d_in[2];      // [4,1024,1024]
  const float* in_proj_w = (const float*)d_in[3];  // [1536,512]
  const float* in_proj_b = (const float*)d_in[4];  // [1536]
  const float* out_w = (const float*)d_in[5];      // [512,512]
  const float* out_b = (const float*)d_in[6];      // [512]
  float* out = (float*)d_out;                      // [4,1024,512]

  unsigned char* ws = (unsigned char*)d_ws;
  unsigned short* qkb   = (unsigned short*)(ws);                     // 8 MB
  unsigned short* xb    = (unsigned short*)(ws + (8ull << 20));      // 4 MB
  unsigned short* W1b   = (unsigned short*)(ws + (12ull << 20));     // 1 MB
  unsigned short* Wob   = (unsigned short*)(ws + (13ull << 20));     // 0.5 MB
  unsigned short* Vt    = (unsigned short*)(ws + (14ull << 20));     // 4 MB
  unsigned short* attnb = (unsigned short*)(ws + (18ull << 20));     // 4 MB
  unsigned char*  Mpack = ws + (38ull << 20) + (256u << 10);         // 512 KB

  prep<<<3968, 256, 0, stream>>>(x, in_proj_w, out_w, Mmask, V,
                                 xb, W1b, Wob, Mpack, Vt);
  gemm_qk<<<dim3(16, 32), 256, 0, stream>>>(xb, W1b, in_proj_b, qkb);
  flash_attn_fused<<<dim3(SS / 64, HH, BB), 256, 0, stream>>>(
      qkb, Vt, Mpack, attnb);
  gemm_out<<<dim3(8, 64), 256, 0, stream>>>(attnb, Wob, out_b, out);
}